// Round 9
// baseline (164.903 us; speedup 1.0000x reference)
//
#include <hip/hip_runtime.h>
#include <stdint.h>

#define B_ROWS 8192
#define H_DIM 1024
#define L_DIM 1024
#define NH 5

typedef float f32x4 __attribute__((ext_vector_type(4)));
typedef int i32x8 __attribute__((ext_vector_type(8)));

typedef const __attribute__((address_space(1))) unsigned int* gas_uint_ptr;
typedef __attribute__((address_space(3))) unsigned int* las_uint_ptr;

__device__ __forceinline__ void load_lds16(const void* gsrc, void* ldst) {
  __builtin_amdgcn_global_load_lds((gas_uint_ptr)(uintptr_t)gsrc,
                                   (las_uint_ptr)(uintptr_t)ldst, 16, 0, 0);
}

// pack 4 fp32 -> 4 OCP e4m3 in one uint (byte i = element i) — R5-verified
__device__ __forceinline__ unsigned int pack_fp8x4(float4 f) {
  int r = __builtin_amdgcn_cvt_pk_fp8_f32(f.x, f.y, 0, false);
  r = __builtin_amdgcn_cvt_pk_fp8_f32(f.z, f.w, r, true);
  return (unsigned int)r;
}

// ---- kernel 1: fused streaming convert + bucket (fp8 variant) ----
// blocks [0,512):     W fp32->fp8, grid-stride, 10 uint/thread
// blocks [512,1536):  8 rows/block; g==5 -> fill out with label, else hidden->fp8 Hb
// blocks [1536,1568): bucket rows by group (LDS-aggregated, 5 global atomics/block)
__global__ void k_conv(const float* __restrict__ hidden, const float* __restrict__ W,
                       const int* __restrict__ group, const int* __restrict__ labels,
                       int* __restrict__ cnt, int* __restrict__ rowlist,
                       unsigned char* __restrict__ Hb, unsigned char* __restrict__ Wb,
                       float* __restrict__ out) {
  const int blk = blockIdx.x;
  const int t = threadIdx.x;
  if (blk < 512) {
    const float4* src = (const float4*)W;
    unsigned int* dst = (unsigned int*)Wb;
#pragma unroll
    for (int i = 0; i < 10; i++) {
      int idx = (i * 512 + blk) * 256 + t;   // 512*256*10 = 1,310,720 float4 = all of W
      dst[idx] = pack_fp8x4(src[idx]);
    }
  } else if (blk < 1536) {
    const int rb = (blk - 512) * 8;
    int gs[8];
#pragma unroll
    for (int r = 0; r < 8; r++) gs[r] = group[rb + r];   // independent loads up front
#pragma unroll
    for (int r = 0; r < 8; r++) {
      int row = rb + r;
      if (gs[r] == NH) {
        float v = (float)labels[row];
        ((float4*)(out + (size_t)row * L_DIM))[t] = make_float4(v, v, v, v);
      } else {
        float4 h = ((const float4*)(hidden + (size_t)row * H_DIM))[t];
        ((unsigned int*)(Hb + (size_t)row * H_DIM))[t] = pack_fp8x4(h);
      }
    }
  } else {
    __shared__ int lcnt[NH];
    __shared__ int lbase[NH];
    if (t < NH) lcnt[t] = 0;
    __syncthreads();
    int b = (blk - 1536) * 256 + t;
    int g = group[b];
    int lpos = -1;
    if (g < NH) lpos = atomicAdd(&lcnt[g], 1);
    __syncthreads();
    if (t < NH) lbase[t] = atomicAdd(&cnt[t], lcnt[t]);
    __syncthreads();
    if (g < NH) rowlist[g * B_ROWS + lbase[g] + lpos] = b;
  }
}

// ---- kernel 2: bucketed MX-fp8 MFMA GEMM, 128x128 tile, BK=128, double-buffered ----
// R5 verified the f8f6f4 numerics/layout; its slowness was register-assembly
// spill from the 16B-granularity swizzle. Fix: XOR-swizzle at 32B granularity —
// LDS 16B-slot s of row r holds global chunk ((s>>1)^(r&3))*2+(s&1), so each
// A/B fragment (K=128, 32B/lane) is ONE contiguous aligned i32x8 LDS read
// (2 consecutive ds_read_b128, no element inserts). 4-way read conflicts
// (1.58x, m136) hide under the K=128 MFMAs. 8 K-iters (half the barriers of
// bf16 BK=64), staging volume halved: 220 MB -> 110 MB.
__global__ __launch_bounds__(256, 2)
void k_gemm(const unsigned char* __restrict__ Hb, const unsigned char* __restrict__ Wb,
            const float* __restrict__ bias, const int* __restrict__ cnt,
            const int* __restrict__ rowlist, float* __restrict__ out) {
  const int head = blockIdx.z;
  const int cntg = cnt[head];
  const int rowbase = blockIdx.y * 128;
  if (rowbase >= cntg) return;
  const int n0 = blockIdx.x * 128;

  __shared__ __align__(32) unsigned char As[2][128 * 128];  // 16 KB x2
  __shared__ __align__(32) unsigned char Bs[2][128 * 128];  // 16 KB x2

  const int t = threadIdx.x;
  const int wave = t >> 6, lane = t & 63;
  const int quad = lane >> 4, c16 = lane & 15;
  const int wm = (wave & 1) * 64, wn = (wave >> 1) * 64;

  const unsigned char* Wg = Wb + (size_t)head * L_DIM * H_DIM;
  const int* rl = rowlist + head * B_ROWS;

  // per-thread staging sources (loop-invariant; +kt bytes per iteration)
  const unsigned char* srcA[4];
  const unsigned char* srcB[4];
  int ldso[4];
#pragma unroll
  for (int p = 0; p < 4; p++) {
    int c = p * 256 + t;                  // 16B slot id 0..1023 (row = c>>3, s = c&7)
    int row = c >> 3;
    int s = c & 7;
    int g = (((s >> 1) ^ (row & 3)) << 1) | (s & 1);  // source chunk16 (32B-swizzle)
    int ks = g * 16;                      // source byte offset within 128B K-slice
    int idx = rowbase + row;
    idx = idx < cntg ? idx : cntg - 1;    // clamp into valid rowlist entries
    srcA[p] = Hb + (size_t)rl[idx] * H_DIM + ks;
    srcB[p] = Wg + (size_t)(n0 + row) * H_DIM + ks;
    ldso[p] = c * 16;                     // lane-linear LDS dst (bytes)
  }

  f32x4 acc[4][4] = {};
  const int sc1 = 0x7F7F7F7F;             // e8m0 127 = x1.0, replicated (R5-verified)

  // prologue: stage K-tile 0
#pragma unroll
  for (int p = 0; p < 4; p++) {
    load_lds16(srcA[p], &As[0][ldso[p]]);
    load_lds16(srcB[p], &Bs[0][ldso[p]]);
  }
  __syncthreads();

  for (int kt = 0; kt < H_DIM; kt += 128) {
    const int cur = (kt >> 7) & 1;
    if (kt + 128 < H_DIM) {
      const int nxt = cur ^ 1;
#pragma unroll
      for (int p = 0; p < 4; p++) {
        load_lds16(srcA[p] + kt + 128, &As[nxt][ldso[p]]);
        load_lds16(srcB[p] + kt + 128, &Bs[nxt][ldso[p]]);
      }
    }
    {
      const int sw = c16 & 3;             // row&3 == c16&3 for all frag rows
      const int cl = (quad ^ sw) * 32;    // 32B-slot of this quad's K-slice
      i32x8 af[4], bf[4];
#pragma unroll
      for (int i = 0; i < 4; i++)
        af[i] = *(const i32x8*)(&As[cur][(wm + i * 16 + c16) * 128 + cl]);
#pragma unroll
      for (int j = 0; j < 4; j++)
        bf[j] = *(const i32x8*)(&Bs[cur][(wn + j * 16 + c16) * 128 + cl]);
#pragma unroll
      for (int i = 0; i < 4; i++)
#pragma unroll
        for (int j = 0; j < 4; j++)
          acc[i][j] = __builtin_amdgcn_mfma_scale_f32_16x16x128_f8f6f4(
              af[i], bf[j], acc[i][j], 0 /*fmtA=fp8*/, 0 /*fmtB=fp8*/,
              0, sc1, 0, sc1);
    }
    __syncthreads();   // drains prefetch vmcnt (overlapped with compute above)
  }

  // epilogue: C/D layout col=lane&15, row=quad*4+reg (R5-verified for f8f6f4);
  // scatter through rowlist, add bias
#pragma unroll
  for (int i = 0; i < 4; i++) {
    int rloc0 = wm + i * 16 + quad * 4;
#pragma unroll
    for (int r = 0; r < 4; r++) {
      int idx = rloc0 + r;
      if (rowbase + idx < cntg) {
        int orow = rl[rowbase + idx];
        float* orowp = out + (size_t)orow * L_DIM + n0;
#pragma unroll
        for (int j = 0; j < 4; j++) {
          int n = wn + j * 16 + c16;
          orowp[n] = acc[i][j][r] + bias[head * L_DIM + n0 + n];
        }
      }
    }
  }
}

extern "C" void kernel_launch(void* const* d_in, const int* in_sizes, int n_in,
                              void* d_out, int out_size, void* d_ws, size_t ws_size,
                              hipStream_t stream) {
  const float* hidden = (const float*)d_in[0];
  const float* W      = (const float*)d_in[1];
  const float* bias   = (const float*)d_in[2];
  const int* group    = (const int*)d_in[3];
  const int* labels   = (const int*)d_in[4];
  float* out = (float*)d_out;

  // ws layout: [cnt 64B][rowlist 5*8192*4B @256][Wb fp8 @256KB (5MB)][Hb fp8 @256KB+6MB (8MB)]
  char* ws = (char*)d_ws;
  int* cnt = (int*)ws;
  int* rowlist = (int*)(ws + 256);
  unsigned char* Wb = (unsigned char*)(ws + (1 << 18));
  unsigned char* Hb = (unsigned char*)(ws + (1 << 18) + (6u << 20));

  hipMemsetAsync(cnt, 0, 64, stream);
  k_conv<<<1568, 256, 0, stream>>>(hidden, W, group, labels, cnt, rowlist, Hb, Wb, out);
  k_gemm<<<dim3(L_DIM / 128, B_ROWS / 128, NH), 256, 0, stream>>>(Hb, Wb, bias, cnt, rowlist, out);
}